// Round 14
// baseline (159.796 us; speedup 1.0000x reference)
//
#include <hip/hip_runtime.h>
#include <stdint.h>

// B=8, S=2048, F=512, D=128, C=1000. I/O fp32; internal bf16 MFMA, fp32 accum.
// mean-attention restructure: w[k] = sum_s exp(S[s,k]-10)/l[s];
// sum_s attn_out = w . V  (V consumed row-major).
// LDS tiles = XOR-swizzled 16B chunks: chunk (r,c) at r*C + (c ^ (r & (C-1))).
// Attention passes: 4 m-frags/wave (256 q-rows/block), KC=16 -> 1024 blocks.
#define NB 8
#define SS 2048
#define FF 512
#define DD 128
#define CC 1000
#define KC 16             // KV split factor
#define CHUNK (SS / KC)   // 128

typedef __attribute__((ext_vector_type(8))) short bf16x8;
typedef __attribute__((ext_vector_type(4))) float f32x4;

__device__ __forceinline__ short f2bf(float f) {
    uint32_t u;
    __builtin_memcpy(&u, &f, 4);
    u = (u + 0x7fffu + ((u >> 16) & 1u)) >> 16;   // RNE
    return (short)u;
}
__device__ __forceinline__ float bf2f(short h) {
    uint32_t u = ((uint32_t)(uint16_t)h) << 16;
    float f;
    __builtin_memcpy(&f, &u, 4);
    return f;
}
// async 16B global->LDS; LDS dest = wave-uniform base + lane*16
__device__ __forceinline__ void async16(const void* g, void* l) {
    __builtin_amdgcn_global_load_lds(
        (const __attribute__((address_space(1))) uint32_t*)g,
        (__attribute__((address_space(3))) uint32_t*)l, 16, 0, 0);
}

// ---------------------------------------------------------------------------
// Kernel 0 (prep): cast x fp32->bf16 (blocks 0..4095) and transpose+cast the
// projection weights [F][D]f32 -> [D][F]bf16 (blocks 4096..4863).
// ---------------------------------------------------------------------------
__global__ void prep(const float* __restrict__ x,
                     const float* __restrict__ Wq, const float* __restrict__ Wk,
                     const float* __restrict__ Wv,
                     short* __restrict__ xb, short* __restrict__ Wt)
{
    int bx = blockIdx.x;
    if (bx < 4096) {
        int id = bx * 256 + threadIdx.x;
        const float4* src = (const float4*)x + id * 2;
        float4 a = src[0], b2 = src[1];
        bf16x8 o;
        o[0] = f2bf(a.x);  o[1] = f2bf(a.y);  o[2] = f2bf(a.z);  o[3] = f2bf(a.w);
        o[4] = f2bf(b2.x); o[5] = f2bf(b2.y); o[6] = f2bf(b2.z); o[7] = f2bf(b2.w);
        *(bf16x8*)(xb + id * 8) = o;
    } else {
        int id = (bx - 4096) * 256 + threadIdx.x;
        int w = id >> 16, rem = id & 65535;
        int n = rem >> 9, kx = rem & 511;
        const float* Wsrc = (w == 0) ? Wq : (w == 1) ? Wk : Wv;
        Wt[w * 65536 + n * 512 + kx] = f2bf(Wsrc[kx * 128 + n]);
    }
}

// ---------------------------------------------------------------------------
// Kernel 1: fused QKV projection via swizzled global_load_lds.
// C[16384x128] = xb[16384x512] @ Wt^T + bias. grid (128 m-tiles, 3 mats).
// ALL outputs row-major [s][d] (coalesced epilogue).
// ---------------------------------------------------------------------------
__global__ __launch_bounds__(256) void qkv_proj(
    const short* __restrict__ xb, const short* __restrict__ Wt,
    const float* __restrict__ bq, const float* __restrict__ bk, const float* __restrict__ bv,
    short* __restrict__ qo, short* __restrict__ ko, short* __restrict__ vo)
{
    __shared__ __align__(16) short As[128 * 64];   // swizzled chunks, C=8
    __shared__ __align__(16) short Bs[128 * 64];

    const int m0   = blockIdx.x * 128;
    const int mat  = blockIdx.y;
    const int tid  = threadIdx.x;
    const int wave = tid >> 6, lane = tid & 63;
    const int quad = lane >> 4, l16 = lane & 15;
    const int wr = wave >> 1, wc = wave & 1;

    const short* Wm = Wt + mat * 65536;

    f32x4 acc[4][4];
    for (int i = 0; i < 4; i++)
        for (int j = 0; j < 4; j++) acc[i][j] = (f32x4){0.f, 0.f, 0.f, 0.f};

    const int sr = lane >> 3;
    const int sc = (lane & 7) ^ (sr & 7);

    for (int kk = 0; kk < 512; kk += 64) {
        __syncthreads();                           // prior iter frag reads done
        for (int i = 0; i < 4; i++) {
            int ins = wave * 4 + i;                // 0..15
            int r = ins * 8 + sr;
            async16(xb + (m0 + r) * 512 + kk + sc * 8, &As[ins * 512]);
            async16(Wm + r * 512 + kk + sc * 8,        &Bs[ins * 512]);
        }
        __syncthreads();                           // vmcnt drained -> visible

        for (int kc = 0; kc < 2; kc++) {
            bf16x8 af[4], bfr[4];
            for (int mt = 0; mt < 4; mt++) {
                int R = wr * 64 + mt * 16 + l16, cc = kc * 4 + quad;
                af[mt] = *(const bf16x8*)&As[(R * 8 + (cc ^ (R & 7))) * 8];
            }
            for (int nt = 0; nt < 4; nt++) {
                int R = wc * 64 + nt * 16 + l16, cc = kc * 4 + quad;
                bfr[nt] = *(const bf16x8*)&Bs[(R * 8 + (cc ^ (R & 7))) * 8];
            }
            for (int mt = 0; mt < 4; mt++)
                for (int nt = 0; nt < 4; nt++)
                    acc[mt][nt] = __builtin_amdgcn_mfma_f32_16x16x32_bf16(
                        af[mt], bfr[nt], acc[mt][nt], 0, 0, 0);
        }
    }

    const float* bias = (mat == 0) ? bq : (mat == 1) ? bk : bv;
    short* outp = (mat == 0) ? qo : (mat == 1) ? ko : vo;
    for (int mt = 0; mt < 4; mt++) {
        int grow_base = m0 + wr * 64 + mt * 16 + quad * 4;   // C/D row = quad*4+reg
        for (int nt = 0; nt < 4; nt++) {
            int col = wc * 64 + nt * 16 + l16;               // C/D col = lane&15
            float bb = bias[col];
            for (int r = 0; r < 4; r++)
                outp[(grow_base + r) * 128 + col] = f2bf(acc[mt][nt][r] + bb);
        }
    }
}

// ---------------------------------------------------------------------------
// Kernel 2 (pass 1): l_part[kc][b][row] = sum over this KV chunk of
// exp(q_row . k_s - 10).  256 q-rows/block (4 waves x 4 m-frags), KV tile 64.
// Block (0,0,0) also zero-inits accum.  grid = (8, 8, KC) = 1024 blocks.
// ---------------------------------------------------------------------------
__global__ __launch_bounds__(256) void attn_l(
    const short* __restrict__ q, const short* __restrict__ k,
    float* __restrict__ l_part, float* __restrict__ accum)
{
    __shared__ __align__(16) short ks[64 * 128];      // swizzled, C=16

    const int b  = blockIdx.y;
    const int q0 = blockIdx.x * 256;
    const int lq = blockIdx.z;
    const int c0 = lq * CHUNK;
    const int tid  = threadIdx.x;
    const int wave = tid >> 6, lane = tid & 63;
    const int quad = lane >> 4, l16 = lane & 15;

    if (blockIdx.x == 0 && blockIdx.y == 0 && blockIdx.z == 0) {
        accum[tid] = 0.f; accum[256 + tid] = 0.f;
        accum[512 + tid] = 0.f; accum[768 + tid] = 0.f;
    }

    bf16x8 qf[4][4];
    for (int m = 0; m < 4; m++)
        for (int c = 0; c < 4; c++)
            qf[m][c] = *(const bf16x8*)(q + (b * 2048 + q0 + wave * 64 + m * 16 + l16) * 128
                                          + c * 32 + quad * 8);

    float lsum[4][4];
    for (int m = 0; m < 4; m++)
        for (int r = 0; r < 4; r++) lsum[m][r] = 0.f;
    const int krl = lane >> 4;                        // 0..3

    for (int s0 = c0; s0 < c0 + CHUNK; s0 += 64) {
        __syncthreads();
        for (int i = 0; i < 4; i++) {
            int ik = wave * 4 + i;                    // 0..15
            int kr = ik * 4 + krl;                    // 0..63
            int kc8 = (lane & 15) ^ (kr & 15);
            async16(k + (b * 2048 + s0 + kr) * 128 + kc8 * 8, &ks[ik * 512]);
        }
        __syncthreads();

        for (int ct = 0; ct < 4; ct++) {
            f32x4 Sf[4];
            for (int m = 0; m < 4; m++) Sf[m] = (f32x4){0.f,0.f,0.f,0.f};
            int R = ct * 16 + l16;                    // R&15 == l16
            for (int c = 0; c < 4; c++) {
                int cc = c * 4 + quad;
                bf16x8 kb = *(const bf16x8*)&ks[(R * 16 + (cc ^ l16)) * 8];
                for (int m = 0; m < 4; m++)
                    Sf[m] = __builtin_amdgcn_mfma_f32_16x16x32_bf16(
                        qf[m][c], kb, Sf[m], 0, 0, 0);
            }
            for (int m = 0; m < 4; m++)
                for (int r = 0; r < 4; r++)
                    lsum[m][r] += __expf(Sf[m][r] - 10.0f);
        }
    }

    for (int m = 0; m < 4; m++)
        for (int r = 0; r < 4; r++) {
            float lv = lsum[m][r];
            lv += __shfl_xor(lv, 1);
            lv += __shfl_xor(lv, 2);
            lv += __shfl_xor(lv, 4);
            lv += __shfl_xor(lv, 8);
            if (l16 == 0)
                l_part[(lq * 8 + b) * 2048 + q0 + wave * 64 + m * 16 + quad * 4 + r] = lv;
        }
}

// ---------------------------------------------------------------------------
// Kernel 3 (pass 2): w_part[qt][b][k] = sum over this block's 256 q-rows of
// exp(S-10)/l_total[row].  Plain stores (unique per block).  grid = (8,8,KC).
// ---------------------------------------------------------------------------
__global__ __launch_bounds__(256) void attn_w(
    const short* __restrict__ q, const short* __restrict__ k,
    const float* __restrict__ l_part, float* __restrict__ w_part)
{
    __shared__ __align__(16) short ks[64 * 128];      // swizzled, C=16
    __shared__ float wl[4][128];

    const int b  = blockIdx.y;
    const int qt = blockIdx.x;
    const int q0 = qt * 256;
    const int lq = blockIdx.z;
    const int c0 = lq * CHUNK;
    const int tid  = threadIdx.x;
    const int wave = tid >> 6, lane = tid & 63;
    const int quad = lane >> 4, l16 = lane & 15;

    bf16x8 qf[4][4];
    for (int m = 0; m < 4; m++)
        for (int c = 0; c < 4; c++)
            qf[m][c] = *(const bf16x8*)(q + (b * 2048 + q0 + wave * 64 + m * 16 + l16) * 128
                                          + c * 32 + quad * 8);

    float linv[4][4];
    for (int m = 0; m < 4; m++)
        for (int r = 0; r < 4; r++) {
            int row = q0 + wave * 64 + m * 16 + quad * 4 + r;
            float lt = 0.f;
            for (int kc = 0; kc < KC; kc++) lt += l_part[(kc * 8 + b) * 2048 + row];
            linv[m][r] = 1.0f / lt;
        }

    const int krl = lane >> 4;

    for (int s0 = c0; s0 < c0 + CHUNK; s0 += 64) {
        __syncthreads();
        for (int i = 0; i < 4; i++) {
            int ik = wave * 4 + i;
            int kr = ik * 4 + krl;
            int kc8 = (lane & 15) ^ (kr & 15);
            async16(k + (b * 2048 + s0 + kr) * 128 + kc8 * 8, &ks[ik * 512]);
        }
        __syncthreads();

        for (int ct = 0; ct < 4; ct++) {
            f32x4 Sf[4];
            for (int m = 0; m < 4; m++) Sf[m] = (f32x4){0.f,0.f,0.f,0.f};
            int R = ct * 16 + l16;
            for (int c = 0; c < 4; c++) {
                int cc = c * 4 + quad;
                bf16x8 kb = *(const bf16x8*)&ks[(R * 16 + (cc ^ l16)) * 8];
                for (int m = 0; m < 4; m++)
                    Sf[m] = __builtin_amdgcn_mfma_f32_16x16x32_bf16(
                        qf[m][c], kb, Sf[m], 0, 0, 0);
            }
            float cs = 0.f;
            for (int m = 0; m < 4; m++)
                for (int r = 0; r < 4; r++)
                    cs += __expf(Sf[m][r] - 10.0f) * linv[m][r];
            cs += __shfl_xor(cs, 16);
            cs += __shfl_xor(cs, 32);
            if (quad == 0) wl[wave][(s0 - c0) + ct * 16 + l16] = cs;
        }
    }

    __syncthreads();
    if (tid < CHUNK) {
        float s = wl[0][tid] + wl[1][tid] + wl[2][tid] + wl[3][tid];
        w_part[(qt * 8 + b) * 2048 + c0 + tid] = s;
    }
}

// ---------------------------------------------------------------------------
// Kernel 4 (wv): accum[b][d] += sum_s w[b][s] * V[b][s][d], V row-major.
// w[b][s] = sum_qt w_part[qt][b][s] (8 q-tiles), staged per-slab in LDS.
// grid (8 batches, 8 s-slabs of 256), 256 threads (128 d x 2 halves).
// ---------------------------------------------------------------------------
__global__ void wv(const float* __restrict__ w_part, const short* __restrict__ vo,
                   float* __restrict__ accum)
{
    __shared__ float wsh[256];
    const int b    = blockIdx.x;
    const int slab = blockIdx.y;
    const int tid  = threadIdx.x;

    int s = slab * 256 + tid;
    float wsum = 0.f;
    for (int qt = 0; qt < 8; qt++) wsum += w_part[(qt * 8 + b) * 2048 + s];
    wsh[tid] = wsum;
    __syncthreads();

    const int d = tid & 127, h = tid >> 7;
    float a = 0.f;
    for (int i = 0; i < 128; i++) {
        int sl = h * 128 + i;
        a += wsh[sl] * bf2f(vo[(size_t)(b * 2048 + slab * 256 + sl) * 128 + d]);
    }
    atomicAdd(&accum[b * 128 + d], a);
}

// ---------------------------------------------------------------------------
// Kernel 5: out[b][c] = (accum[b][:]/2048) . Wl[:,c] + bl[c], fp32 out.
// ---------------------------------------------------------------------------
__global__ void final_proj(const float* __restrict__ accum, const float* __restrict__ Wl,
                           const float* __restrict__ bl, float* __restrict__ out)
{
    int id = blockIdx.x * 256 + threadIdx.x;
    if (id >= NB * CC) return;
    int b = id / CC, c = id % CC;
    float s = 0.f;
    for (int d = 0; d < 128; d++)
        s += accum[b * 128 + d] * Wl[d * 1000 + c];
    out[id] = s * (1.0f / 2048.0f) + bl[c];
}

// ---------------------------------------------------------------------------
extern "C" void kernel_launch(void* const* d_in, const int* in_sizes, int n_in,
                              void* d_out, int out_size, void* d_ws, size_t ws_size,
                              hipStream_t stream) {
    const float* x  = (const float*)d_in[0];
    const float* Wq = (const float*)d_in[1];
    const float* bq = (const float*)d_in[2];
    const float* Wk = (const float*)d_in[3];
    const float* bk = (const float*)d_in[4];
    const float* Wv = (const float*)d_in[5];
    const float* bv = (const float*)d_in[6];
    const float* Wl = (const float*)d_in[7];
    const float* bl = (const float*)d_in[8];
    float* out = (float*)d_out;

    char* ws = (char*)d_ws;
    short* qo     = (short*)(ws);                 // 4 MiB
    short* ko     = (short*)(ws + 4194304);       // 4 MiB
    short* vo     = (short*)(ws + 8388608);       // 4 MiB, row-major [b][s][d]
    short* xb     = (short*)(ws + 12582912);      // 16 MiB (prep+qkv only)
    short* Wt     = (short*)(ws + 29360128);      // 384 KiB
    float* l_part = (float*)(ws + 29753344);      // 1 MiB (KC*8*2048 fp32)
    float* w_part = (float*)(ws + 30801920);      // 512 KiB (8*8*2048 fp32)
    float* acc    = (float*)(ws + 31326208);      // 4 KiB
    // total ~30 MiB of d_ws

    prep<<<4864, 256, 0, stream>>>(x, Wq, Wk, Wv, xb, Wt);
    qkv_proj<<<dim3(128, 3), 256, 0, stream>>>(xb, Wt, bq, bk, bv, qo, ko, vo);
    attn_l<<<dim3(8, 8, KC), 256, 0, stream>>>(qo, ko, l_part, acc);
    attn_w<<<dim3(8, 8, KC), 256, 0, stream>>>(qo, ko, l_part, w_part);
    wv<<<dim3(8, 8), 256, 0, stream>>>(w_part, vo, acc);
    final_proj<<<(NB * CC + 255) / 256, 256, 0, stream>>>(acc, Wl, bl, out);
}

// Round 15
// 153.551 us; speedup vs baseline: 1.0407x; 1.0407x over previous
//
#include <hip/hip_runtime.h>
#include <stdint.h>

// B=8, S=2048, F=512, D=128, C=1000. I/O fp32; internal bf16 MFMA, fp32 accum.
// mean-attention restructure: w[k] = sum_s exp(S[s,k]-10)/l[s];
// sum_s attn_out = w . V  (V consumed row-major -> no transpose scatter).
// LDS tiles = XOR-swizzled 16B chunks: chunk (r,c) at r*C + (c ^ (r & (C-1))).
// Attention passes: 2 m-frags/wave (128 q-rows/block), KC=8 -> 1024 blocks.
// (4 m-frags + KC=16 tried in r14: REGRESSED — prologue amortization halved,
//  Q re-fetch doubled; per-block fixed costs dominate per-MFMA LDS savings.)
#define NB 8
#define SS 2048
#define FF 512
#define DD 128
#define CC 1000
#define KC 8              // KV split factor
#define CHUNK (SS / KC)   // 256

typedef __attribute__((ext_vector_type(8))) short bf16x8;
typedef __attribute__((ext_vector_type(4))) float f32x4;

__device__ __forceinline__ short f2bf(float f) {
    uint32_t u;
    __builtin_memcpy(&u, &f, 4);
    u = (u + 0x7fffu + ((u >> 16) & 1u)) >> 16;   // RNE
    return (short)u;
}
__device__ __forceinline__ float bf2f(short h) {
    uint32_t u = ((uint32_t)(uint16_t)h) << 16;
    float f;
    __builtin_memcpy(&f, &u, 4);
    return f;
}
// async 16B global->LDS; LDS dest = wave-uniform base + lane*16
__device__ __forceinline__ void async16(const void* g, void* l) {
    __builtin_amdgcn_global_load_lds(
        (const __attribute__((address_space(1))) uint32_t*)g,
        (__attribute__((address_space(3))) uint32_t*)l, 16, 0, 0);
}

// ---------------------------------------------------------------------------
// Kernel 0 (prep): cast x fp32->bf16 (blocks 0..4095) and transpose+cast the
// projection weights [F][D]f32 -> [D][F]bf16 (blocks 4096..4863).
// ---------------------------------------------------------------------------
__global__ void prep(const float* __restrict__ x,
                     const float* __restrict__ Wq, const float* __restrict__ Wk,
                     const float* __restrict__ Wv,
                     short* __restrict__ xb, short* __restrict__ Wt)
{
    int bx = blockIdx.x;
    if (bx < 4096) {
        int id = bx * 256 + threadIdx.x;
        const float4* src = (const float4*)x + id * 2;
        float4 a = src[0], b2 = src[1];
        bf16x8 o;
        o[0] = f2bf(a.x);  o[1] = f2bf(a.y);  o[2] = f2bf(a.z);  o[3] = f2bf(a.w);
        o[4] = f2bf(b2.x); o[5] = f2bf(b2.y); o[6] = f2bf(b2.z); o[7] = f2bf(b2.w);
        *(bf16x8*)(xb + id * 8) = o;
    } else {
        int id = (bx - 4096) * 256 + threadIdx.x;
        int w = id >> 16, rem = id & 65535;
        int n = rem >> 9, kx = rem & 511;
        const float* Wsrc = (w == 0) ? Wq : (w == 1) ? Wk : Wv;
        Wt[w * 65536 + n * 512 + kx] = f2bf(Wsrc[kx * 128 + n]);
    }
}

// ---------------------------------------------------------------------------
// Kernel 1: fused QKV projection via swizzled global_load_lds.
// C[16384x128] = xb[16384x512] @ Wt^T + bias. grid (128 m-tiles, 3 mats).
// ALL outputs row-major [s][d] (coalesced epilogue).
// ---------------------------------------------------------------------------
__global__ __launch_bounds__(256) void qkv_proj(
    const short* __restrict__ xb, const short* __restrict__ Wt,
    const float* __restrict__ bq, const float* __restrict__ bk, const float* __restrict__ bv,
    short* __restrict__ qo, short* __restrict__ ko, short* __restrict__ vo)
{
    __shared__ __align__(16) short As[128 * 64];   // swizzled chunks, C=8
    __shared__ __align__(16) short Bs[128 * 64];

    const int m0   = blockIdx.x * 128;
    const int mat  = blockIdx.y;
    const int tid  = threadIdx.x;
    const int wave = tid >> 6, lane = tid & 63;
    const int quad = lane >> 4, l16 = lane & 15;
    const int wr = wave >> 1, wc = wave & 1;

    const short* Wm = Wt + mat * 65536;

    f32x4 acc[4][4];
    for (int i = 0; i < 4; i++)
        for (int j = 0; j < 4; j++) acc[i][j] = (f32x4){0.f, 0.f, 0.f, 0.f};

    const int sr = lane >> 3;
    const int sc = (lane & 7) ^ (sr & 7);

    for (int kk = 0; kk < 512; kk += 64) {
        __syncthreads();                           // prior iter frag reads done
        for (int i = 0; i < 4; i++) {
            int ins = wave * 4 + i;                // 0..15
            int r = ins * 8 + sr;
            async16(xb + (m0 + r) * 512 + kk + sc * 8, &As[ins * 512]);
            async16(Wm + r * 512 + kk + sc * 8,        &Bs[ins * 512]);
        }
        __syncthreads();                           // vmcnt drained -> visible

        for (int kc = 0; kc < 2; kc++) {
            bf16x8 af[4], bfr[4];
            for (int mt = 0; mt < 4; mt++) {
                int R = wr * 64 + mt * 16 + l16, cc = kc * 4 + quad;
                af[mt] = *(const bf16x8*)&As[(R * 8 + (cc ^ (R & 7))) * 8];
            }
            for (int nt = 0; nt < 4; nt++) {
                int R = wc * 64 + nt * 16 + l16, cc = kc * 4 + quad;
                bfr[nt] = *(const bf16x8*)&Bs[(R * 8 + (cc ^ (R & 7))) * 8];
            }
            for (int mt = 0; mt < 4; mt++)
                for (int nt = 0; nt < 4; nt++)
                    acc[mt][nt] = __builtin_amdgcn_mfma_f32_16x16x32_bf16(
                        af[mt], bfr[nt], acc[mt][nt], 0, 0, 0);
        }
    }

    const float* bias = (mat == 0) ? bq : (mat == 1) ? bk : bv;
    short* outp = (mat == 0) ? qo : (mat == 1) ? ko : vo;
    for (int mt = 0; mt < 4; mt++) {
        int grow_base = m0 + wr * 64 + mt * 16 + quad * 4;   // C/D row = quad*4+reg
        for (int nt = 0; nt < 4; nt++) {
            int col = wc * 64 + nt * 16 + l16;               // C/D col = lane&15
            float bb = bias[col];
            for (int r = 0; r < 4; r++)
                outp[(grow_base + r) * 128 + col] = f2bf(acc[mt][nt][r] + bb);
        }
    }
}

// ---------------------------------------------------------------------------
// Kernel 2 (pass 1): l_part[kc][b][row] = sum over this KV chunk of
// exp(q_row . k_s - 10).  128 q-rows/block (4 waves x 2 m-frags), KV tile 64.
// Block (0,0,0) also zero-inits accum (saves a memset dispatch).
// grid = (16 q-tiles, 8 batches, KC) = 1024 blocks.
// ---------------------------------------------------------------------------
__global__ __launch_bounds__(256) void attn_l(
    const short* __restrict__ q, const short* __restrict__ k,
    float* __restrict__ l_part, float* __restrict__ accum)
{
    __shared__ __align__(16) short ks[64 * 128];      // swizzled, C=16

    const int b  = blockIdx.y;
    const int q0 = blockIdx.x * 128;
    const int lq = blockIdx.z;
    const int c0 = lq * CHUNK;
    const int tid  = threadIdx.x;
    const int wave = tid >> 6, lane = tid & 63;
    const int quad = lane >> 4, l16 = lane & 15;

    if (blockIdx.x == 0 && blockIdx.y == 0 && blockIdx.z == 0) {
        accum[tid] = 0.f; accum[256 + tid] = 0.f;
        accum[512 + tid] = 0.f; accum[768 + tid] = 0.f;
    }

    bf16x8 qf[2][4];
    for (int m = 0; m < 2; m++)
        for (int c = 0; c < 4; c++)
            qf[m][c] = *(const bf16x8*)(q + (b * 2048 + q0 + wave * 32 + m * 16 + l16) * 128
                                          + c * 32 + quad * 8);

    float lsum[2][4] = {{0.f,0.f,0.f,0.f},{0.f,0.f,0.f,0.f}};
    const int krl = lane >> 4;                        // 0..3

    for (int s0 = c0; s0 < c0 + CHUNK; s0 += 64) {
        __syncthreads();
        for (int i = 0; i < 4; i++) {
            int ik = wave * 4 + i;                    // 0..15
            int kr = ik * 4 + krl;                    // 0..63
            int kc8 = (lane & 15) ^ (kr & 15);
            async16(k + (b * 2048 + s0 + kr) * 128 + kc8 * 8, &ks[ik * 512]);
        }
        __syncthreads();

        for (int ct = 0; ct < 4; ct++) {
            f32x4 Sf[2];
            Sf[0] = (f32x4){0.f,0.f,0.f,0.f};
            Sf[1] = (f32x4){0.f,0.f,0.f,0.f};
            int R = ct * 16 + l16;                    // R&15 == l16
            for (int c = 0; c < 4; c++) {
                int cc = c * 4 + quad;
                bf16x8 kb = *(const bf16x8*)&ks[(R * 16 + (cc ^ l16)) * 8];
                for (int m = 0; m < 2; m++)
                    Sf[m] = __builtin_amdgcn_mfma_f32_16x16x32_bf16(
                        qf[m][c], kb, Sf[m], 0, 0, 0);
            }
            for (int m = 0; m < 2; m++)
                for (int r = 0; r < 4; r++)
                    lsum[m][r] += __expf(Sf[m][r] - 10.0f);
        }
    }

    for (int m = 0; m < 2; m++)
        for (int r = 0; r < 4; r++) {
            float lv = lsum[m][r];
            lv += __shfl_xor(lv, 1);
            lv += __shfl_xor(lv, 2);
            lv += __shfl_xor(lv, 4);
            lv += __shfl_xor(lv, 8);
            if (l16 == 0)
                l_part[(lq * 8 + b) * 2048 + q0 + wave * 32 + m * 16 + quad * 4 + r] = lv;
        }
}

// ---------------------------------------------------------------------------
// Kernel 3 (pass 2): w_part[qt][b][k] = sum over this block's 128 q-rows of
// exp(S-10)/l_total[row].  Plain stores (unique per block) -> no atomics,
// no zero-init.  grid = (16, 8, KC).
// ---------------------------------------------------------------------------
__global__ __launch_bounds__(256) void attn_w(
    const short* __restrict__ q, const short* __restrict__ k,
    const float* __restrict__ l_part, float* __restrict__ w_part)
{
    __shared__ __align__(16) short ks[64 * 128];      // swizzled, C=16
    __shared__ float wl[4][256];

    const int b  = blockIdx.y;
    const int qt = blockIdx.x;
    const int q0 = qt * 128;
    const int lq = blockIdx.z;
    const int c0 = lq * CHUNK;
    const int tid  = threadIdx.x;
    const int wave = tid >> 6, lane = tid & 63;
    const int quad = lane >> 4, l16 = lane & 15;

    bf16x8 qf[2][4];
    for (int m = 0; m < 2; m++)
        for (int c = 0; c < 4; c++)
            qf[m][c] = *(const bf16x8*)(q + (b * 2048 + q0 + wave * 32 + m * 16 + l16) * 128
                                          + c * 32 + quad * 8);

    float linv[2][4];
    for (int m = 0; m < 2; m++)
        for (int r = 0; r < 4; r++) {
            int row = q0 + wave * 32 + m * 16 + quad * 4 + r;
            float lt = 0.f;
            for (int kc = 0; kc < KC; kc++) lt += l_part[(kc * 8 + b) * 2048 + row];
            linv[m][r] = 1.0f / lt;
        }

    const int krl = lane >> 4;

    for (int s0 = c0; s0 < c0 + CHUNK; s0 += 64) {
        __syncthreads();
        for (int i = 0; i < 4; i++) {
            int ik = wave * 4 + i;
            int kr = ik * 4 + krl;
            int kc8 = (lane & 15) ^ (kr & 15);
            async16(k + (b * 2048 + s0 + kr) * 128 + kc8 * 8, &ks[ik * 512]);
        }
        __syncthreads();

        for (int ct = 0; ct < 4; ct++) {
            f32x4 Sf[2];
            Sf[0] = (f32x4){0.f,0.f,0.f,0.f};
            Sf[1] = (f32x4){0.f,0.f,0.f,0.f};
            int R = ct * 16 + l16;
            for (int c = 0; c < 4; c++) {
                int cc = c * 4 + quad;
                bf16x8 kb = *(const bf16x8*)&ks[(R * 16 + (cc ^ l16)) * 8];
                for (int m = 0; m < 2; m++)
                    Sf[m] = __builtin_amdgcn_mfma_f32_16x16x32_bf16(
                        qf[m][c], kb, Sf[m], 0, 0, 0);
            }
            float cs = 0.f;
            for (int m = 0; m < 2; m++)
                for (int r = 0; r < 4; r++)
                    cs += __expf(Sf[m][r] - 10.0f) * linv[m][r];
            cs += __shfl_xor(cs, 16);
            cs += __shfl_xor(cs, 32);
            if (quad == 0) wl[wave][(s0 - c0) + ct * 16 + l16] = cs;
        }
    }

    __syncthreads();
    {
        float s = wl[0][tid] + wl[1][tid] + wl[2][tid] + wl[3][tid];
        w_part[(qt * 8 + b) * 2048 + c0 + tid] = s;
    }
}

// ---------------------------------------------------------------------------
// Kernel 4 (wv): accum[b][d] += sum_s w[b][s] * V[b][s][d], V row-major.
// w[b][s] = sum_qt w_part[qt][b][s] (16 q-tiles), staged per-slab in LDS.
// grid (8 batches, 8 s-slabs of 256), 256 threads (128 d x 2 halves).
// ---------------------------------------------------------------------------
__global__ void wv(const float* __restrict__ w_part, const short* __restrict__ vo,
                   float* __restrict__ accum)
{
    __shared__ float wsh[256];
    const int b    = blockIdx.x;
    const int slab = blockIdx.y;
    const int tid  = threadIdx.x;

    int s = slab * 256 + tid;
    float wsum = 0.f;
    for (int qt = 0; qt < 16; qt++) wsum += w_part[(qt * 8 + b) * 2048 + s];
    wsh[tid] = wsum;
    __syncthreads();

    const int d = tid & 127, h = tid >> 7;
    float a = 0.f;
    for (int i = 0; i < 128; i++) {
        int sl = h * 128 + i;
        a += wsh[sl] * bf2f(vo[(size_t)(b * 2048 + slab * 256 + sl) * 128 + d]);
    }
    atomicAdd(&accum[b * 128 + d], a);
}

// ---------------------------------------------------------------------------
// Kernel 5: out[b][c] = (accum[b][:]/2048) . Wl[:,c] + bl[c], fp32 out.
// ---------------------------------------------------------------------------
__global__ void final_proj(const float* __restrict__ accum, const float* __restrict__ Wl,
                           const float* __restrict__ bl, float* __restrict__ out)
{
    int id = blockIdx.x * 256 + threadIdx.x;
    if (id >= NB * CC) return;
    int b = id / CC, c = id % CC;
    float s = 0.f;
    for (int d = 0; d < 128; d++)
        s += accum[b * 128 + d] * Wl[d * 1000 + c];
    out[id] = s * (1.0f / 2048.0f) + bl[c];
}

// ---------------------------------------------------------------------------
extern "C" void kernel_launch(void* const* d_in, const int* in_sizes, int n_in,
                              void* d_out, int out_size, void* d_ws, size_t ws_size,
                              hipStream_t stream) {
    const float* x  = (const float*)d_in[0];
    const float* Wq = (const float*)d_in[1];
    const float* bq = (const float*)d_in[2];
    const float* Wk = (const float*)d_in[3];
    const float* bk = (const float*)d_in[4];
    const float* Wv = (const float*)d_in[5];
    const float* bv = (const float*)d_in[6];
    const float* Wl = (const float*)d_in[7];
    const float* bl = (const float*)d_in[8];
    float* out = (float*)d_out;

    char* ws = (char*)d_ws;
    short* qo     = (short*)(ws);                 // 4 MiB
    short* ko     = (short*)(ws + 4194304);       // 4 MiB
    short* vo     = (short*)(ws + 8388608);       // 4 MiB, row-major [b][s][d]
    short* xb     = (short*)(ws + 12582912);      // 16 MiB (prep+qkv only)
    short* Wt     = (short*)(ws + 29360128);      // 384 KiB
    float* l_part = (float*)(ws + 29753344);      // 512 KiB (KC*8*2048 fp32)
    float* w_part = (float*)(ws + 30277632);      // 1 MiB (16*8*2048 fp32)
    float* acc    = (float*)(ws + 31326208);      // 4 KiB
    // total ~30 MiB of d_ws

    prep<<<4864, 256, 0, stream>>>(x, Wq, Wk, Wv, xb, Wt);
    qkv_proj<<<dim3(128, 3), 256, 0, stream>>>(xb, Wt, bq, bk, bv, qo, ko, vo);
    attn_l<<<dim3(16, 8, KC), 256, 0, stream>>>(qo, ko, l_part, acc);
    attn_w<<<dim3(16, 8, KC), 256, 0, stream>>>(qo, ko, l_part, w_part);
    wv<<<dim3(8, 8), 256, 0, stream>>>(w_part, vo, acc);
    final_proj<<<(NB * CC + 255) / 256, 256, 0, stream>>>(acc, Wl, bl, out);
}